// Round 11
// baseline (2565.658 us; speedup 1.0000x reference)
//
#include <hip/hip_runtime.h>

#define BB 8
#define NN 4096
#define DD 64
#define SS 1024
#define KK 32
#define GINF 1e30f

typedef float f32x2 __attribute__((ext_vector_type(2)));

__device__ __forceinline__ float fmulrn(float a, float b){ return __fmul_rn(a,b); }
__device__ __forceinline__ float faddrn(float a, float b){ return __fadd_rn(a,b); }
__device__ __forceinline__ float fsubrn(float a, float b){ return __fsub_rn(a,b); }

// CDNA3+ full-rate packed FP32 (VOP3P). IEEE RN per half == scalar ops.
__device__ __forceinline__ f32x2 pk_add(f32x2 a, f32x2 b){
  f32x2 d; asm("v_pk_add_f32 %0, %1, %2" : "=v"(d) : "v"(a), "v"(b)); return d;
}
__device__ __forceinline__ f32x2 pk_mul(f32x2 a, f32x2 b){
  f32x2 d; asm("v_pk_mul_f32 %0, %1, %2" : "=v"(d) : "v"(a), "v"(b)); return d;
}

// one DPP max step: v_mov_b32_dpp (zero-fill OOB, valid since dists >= 0) + v_max_f32
template<int CTRL>
__device__ __forceinline__ float dpp_fmax(float v){
  int o = __builtin_amdgcn_update_dpp(0, __float_as_int(v), CTRL, 0xf, 0xf, true);
  return fmaxf(v, __int_as_float(o));
}

__device__ __forceinline__ float wave_max_dpp(float lm){
  float v = lm;
  v = dpp_fmax<0x111>(v);   // row_shr:1
  v = dpp_fmax<0x112>(v);   // row_shr:2
  v = dpp_fmax<0x114>(v);   // row_shr:4
  v = dpp_fmax<0x118>(v);   // row_shr:8
  v = dpp_fmax<0x142>(v);   // row_bcast:15
  v = dpp_fmax<0x143>(v);   // row_bcast:31  -> lane 63 has wave max
  return __int_as_float(__builtin_amdgcn_readlane(__float_as_int(v), 63));
}

// exact IEEE negation (sign-bit flip): a + (-c) is bitwise identical to a - c
__device__ __forceinline__ float fneg_exact(float c){
  return __int_as_float(__float_as_int(c) ^ 0x80000000);
}

// ---------------- |x|^2 precompute (exact op order: ((x*x + y*y) + z*z)) ----------------
__global__ __launch_bounds__(256) void sqx_kernel(const float* __restrict__ xyz,
                                                  float* __restrict__ sqx){
  int i = blockIdx.x * 256 + threadIdx.x;         // 0 .. B*N-1
  int b = i >> 12, n = i & (NN - 1);
  const float* xb = xyz + b * 3 * NN;
  float x = xb[n], y = xb[NN + n], z = xb[2 * NN + n];
  sqx[i] = faddrn(faddrn(fmulrn(x, x), fmulrn(y, y)), fmulrn(z, z));
}

// ---------------- FPS: 2 batches per block, interleaved (fills dep-latency stalls) --------
// R10 heater experiment showed ~75% of per-iter cycles are unfillable stalls at 1 wave/SIMD
// with a single dependency stream. Two independent batch streams per block share one
// barrier per round; each stream's bubbles are filled by the other's instructions.
// Per-batch math/tie-rules identical to the proven R2/R7/R9 kernels (absmax=0).
__global__ __launch_bounds__(256) void fps_kernel(const float* __restrict__ xyz,
                                                  const int* __restrict__ finit,
                                                  int* __restrict__ fps_idx){
  __shared__ float4 scA[2][4], scB[2][4];   // per-wave candidates {cx,cy,cz,val}, parity-dbl
  __shared__ int    snA[2][4], snB[2][4];
  int blk = blockIdx.x, tid = threadIdx.x;
  int lane = tid & 63, w = tid >> 6;
  int bA = blk * 2, bB = blk * 2 + 1;
  const float* xA = xyz + bA * 3 * NN;
  const float* xB = xyz + bB * 3 * NN;
  int nbase = tid << 4;

  f32x2 pxA[8], pyA[8], pzA[8], ddA[8];
  f32x2 pxB[8], pyB[8], pzB[8], ddB[8];
  #pragma unroll
  for (int p = 0; p < 8; ++p){
    pxA[p] = ((const f32x2*)(xA + nbase))[p];
    pyA[p] = ((const f32x2*)(xA + NN + nbase))[p];
    pzA[p] = ((const f32x2*)(xA + 2 * NN + nbase))[p];
    pxB[p] = ((const f32x2*)(xB + nbase))[p];
    pyB[p] = ((const f32x2*)(xB + NN + nbase))[p];
    pzB[p] = ((const f32x2*)(xB + 2 * NN + nbase))[p];
    ddA[p] = (f32x2){1e10f, 1e10f};          // matches jnp.full(..., 1e10, f32)
    ddB[p] = (f32x2){1e10f, 1e10f};
  }
  int farA = finit[bA], farB = finit[bB];
  float cxA = xA[farA], cyA = xA[NN + farA], czA = xA[2 * NN + farA];
  float cxB = xB[farB], cyB = xB[NN + farB], czB = xB[2 * NN + farB];
  if (tid == 0){ fps_idx[bA * SS] = farA; fps_idx[bB * SS] = farB; }

  for (int it = 0; it < SS - 1; ++it){
    // ---- packed updates, batch A then B (independent streams; scheduler interleaves) ----
    f32x2 ncxA = {fneg_exact(cxA), fneg_exact(cxA)};
    f32x2 ncyA = {fneg_exact(cyA), fneg_exact(cyA)};
    f32x2 nczA = {fneg_exact(czA), fneg_exact(czA)};
    f32x2 ncxB = {fneg_exact(cxB), fneg_exact(cxB)};
    f32x2 ncyB = {fneg_exact(cyB), fneg_exact(cyB)};
    f32x2 nczB = {fneg_exact(czB), fneg_exact(czB)};
    float lmxA = 0.f, lmyA = 0.f, lmxB = 0.f, lmyB = 0.f;   // 0 valid identity: dists >= 0
    #pragma unroll
    for (int p = 0; p < 8; ++p){
      f32x2 tx = pk_add(pxA[p], ncxA);
      f32x2 ty = pk_add(pyA[p], ncyA);
      f32x2 tz = pk_add(pzA[p], nczA);
      f32x2 d2 = pk_add(pk_add(pk_mul(tx, tx), pk_mul(ty, ty)), pk_mul(tz, tz));
      ddA[p].x = fminf(ddA[p].x, d2.x);
      ddA[p].y = fminf(ddA[p].y, d2.y);
      lmxA = fmaxf(lmxA, ddA[p].x);
      lmyA = fmaxf(lmyA, ddA[p].y);
    }
    #pragma unroll
    for (int p = 0; p < 8; ++p){
      f32x2 tx = pk_add(pxB[p], ncxB);
      f32x2 ty = pk_add(pyB[p], ncyB);
      f32x2 tz = pk_add(pzB[p], nczB);
      f32x2 d2 = pk_add(pk_add(pk_mul(tx, tx), pk_mul(ty, ty)), pk_mul(tz, tz));
      ddB[p].x = fminf(ddB[p].x, d2.x);
      ddB[p].y = fminf(ddB[p].y, d2.y);
      lmxB = fmaxf(lmxB, ddB[p].x);
      lmyB = fmaxf(lmyB, ddB[p].y);
    }
    float lmA = fmaxf(lmxA, lmyA);
    float lmB = fmaxf(lmxB, lmyB);

    // ---- lm-keyed first-match rescans (independent of DPP trees; R9-proven) ----
    int locA1 = -1, locA2 = -1, locB1 = -1, locB2 = -1;
    float a1x=0.f,a1y=0.f,a1z=0.f, a2x=0.f,a2y=0.f,a2z=0.f;
    float b1x=0.f,b1y=0.f,b1z=0.f, b2x=0.f,b2y=0.f,b2z=0.f;
    #pragma unroll
    for (int j = 15; j >= 8; --j){
      int p = j >> 1;
      float dv = (j & 1) ? ddA[p].y : ddA[p].x;
      if (dv == lmA){ locA2 = j;
        a2x = (j & 1) ? pxA[p].y : pxA[p].x;
        a2y = (j & 1) ? pyA[p].y : pyA[p].x;
        a2z = (j & 1) ? pzA[p].y : pzA[p].x; }
    }
    #pragma unroll
    for (int j = 7; j >= 0; --j){
      int p = j >> 1;
      float dv = (j & 1) ? ddA[p].y : ddA[p].x;
      if (dv == lmA){ locA1 = j;
        a1x = (j & 1) ? pxA[p].y : pxA[p].x;
        a1y = (j & 1) ? pyA[p].y : pyA[p].x;
        a1z = (j & 1) ? pzA[p].y : pzA[p].x; }
    }
    #pragma unroll
    for (int j = 15; j >= 8; --j){
      int p = j >> 1;
      float dv = (j & 1) ? ddB[p].y : ddB[p].x;
      if (dv == lmB){ locB2 = j;
        b2x = (j & 1) ? pxB[p].y : pxB[p].x;
        b2y = (j & 1) ? pyB[p].y : pyB[p].x;
        b2z = (j & 1) ? pzB[p].y : pzB[p].x; }
    }
    #pragma unroll
    for (int j = 7; j >= 0; --j){
      int p = j >> 1;
      float dv = (j & 1) ? ddB[p].y : ddB[p].x;
      if (dv == lmB){ locB1 = j;
        b1x = (j & 1) ? pxB[p].y : pxB[p].x;
        b1y = (j & 1) ? pyB[p].y : pyB[p].x;
        b1z = (j & 1) ? pzB[p].y : pzB[p].x; }
    }
    bool faA = locA1 >= 0;
    int   jlocA = faA ? locA1 : locA2;
    float sAx = faA ? a1x : a2x, sAy = faA ? a1y : a2y, sAz = faA ? a1z : a2z;
    bool faB = locB1 >= 0;
    int   jlocB = faB ? locB1 : locB2;
    float sBx = faB ? b1x : b2x, sBy = faB ? b1y : b2y, sBz = faB ? b1z : b2z;

    // ---- wave maxima via DPP trees (two independent chains overlap) ----
    float maxvA = wave_max_dpp(lmA);
    float maxvB = wave_max_dpp(lmB);

    // ---- winner lanes (exact bit equality; first lane == smallest n) ----
    unsigned long long balA = __ballot(lmA == maxvA);
    unsigned long long balB = __ballot(lmB == maxvB);
    int flA = __ffsll(balA) - 1;
    int flB = __ffsll(balB) - 1;
    int par = it & 1;
    if (lane == flA){ scA[par][w] = make_float4(sAx, sAy, sAz, maxvA); snA[par][w] = nbase + jlocA; }
    if (lane == flB){ scB[par][w] = make_float4(sBx, sBy, sBz, maxvB); snB[par][w] = nbase + jlocB; }
    __syncthreads();                         // ONE barrier per round serves both batches

    // ---- combines: slot order == ascending n-range, strict > implements tie rule ----
    float4 s0 = scA[par][0]; int n0 = snA[par][0];
    #pragma unroll
    for (int q = 1; q < 4; ++q){
      float4 sq_ = scA[par][q]; int nq = snA[par][q];
      if (sq_.w > s0.w){ s0 = sq_; n0 = nq; }
    }
    cxA = s0.x; cyA = s0.y; czA = s0.z;
    float4 t0 = scB[par][0]; int m0 = snB[par][0];
    #pragma unroll
    for (int q = 1; q < 4; ++q){
      float4 tq_ = scB[par][q]; int mq = snB[par][q];
      if (tq_.w > t0.w){ t0 = tq_; m0 = mq; }
    }
    cxB = t0.x; cyB = t0.y; czB = t0.z;
    if (tid == 0){
      fps_idx[bA * SS + it + 1] = n0;        // queued stores, hidden under next update
      fps_idx[bB * SS + it + 1] = m0;
    }
  }
}

// ---------------- kNN (top-32 by expanded sq-dist) + gather + feature max ----------------
__global__ __launch_bounds__(256) void knn_kernel(const float* __restrict__ xyz,
                                                  const float* __restrict__ points,
                                                  const float* __restrict__ sqx,
                                                  const int* __restrict__ fps_idx,
                                                  float* __restrict__ out){
  __shared__ int nbr[4][KK];
  int tid = threadIdx.x;
  int lane = tid & 63, wslot = tid >> 6;
  int gw = blockIdx.x * 4 + wslot;           // 0 .. 8191
  int b = gw >> 10, cs = gw & 1023;
  const float* xb = xyz + b * 3 * NN;
  const float* sb = sqx + b * NN;
  int c0 = fps_idx[b * SS + cs];
  float cx = xb[c0], cy = xb[NN + c0], cz = xb[2 * NN + c0];
  float sqc = sb[c0];

  float d[64];
  #pragma unroll
  for (int k = 0; k < 64; ++k){
    int n = (k << 6) | lane;
    float xn = xb[n], yn = xb[NN + n], zn = xb[2 * NN + n], sn = sb[n];
    float dot = faddrn(faddrn(fmulrn(cx, xn), fmulrn(cy, yn)), fmulrn(cz, zn));
    d[k] = fsubrn(faddrn(sqc, sn), fmulrn(2.0f, dot));
  }

  float gv[8]; int gn[8];
  #pragma unroll
  for (int j = 0; j < 8; ++j){
    float nv = GINF; int nn2 = 0x40000000;
    #pragma unroll
    for (int t = 0; t < 8; ++t){
      int k = j * 8 + t; int n = (k << 6) | lane;
      if (d[k] < nv){ nv = d[k]; nn2 = n; }
    }
    gv[j] = nv; gn[j] = nn2;
  }

  float lv = -GINF; int ln = -1;
  for (int r = 0; r < KK; ++r){
    float bv = gv[0]; int bn = gn[0];
    #pragma unroll
    for (int j = 1; j < 8; ++j){ if (gv[j] < bv){ bv = gv[j]; bn = gn[j]; } }
    #pragma unroll
    for (int m = 1; m < 64; m <<= 1){
      float ov = __shfl_xor(bv, m);
      int   on = __shfl_xor(bn, m);
      if (ov < bv || (ov == bv && on < bn)){ bv = ov; bn = on; }
    }
    if (lane == 0) nbr[wslot][r] = bn;
    lv = bv; ln = bn;
    int jsel = __builtin_amdgcn_readfirstlane(bn >> 9);
    #define RECOMP(J) if (jsel == (J)) { float nv = GINF; int nn2 = 0x40000000; \
      _Pragma("unroll") \
      for (int t = 0; t < 8; ++t){ int k = (J) * 8 + t; int n = (k << 6) | lane; \
        bool pass = (d[k] > lv) || (d[k] == lv && n > ln); \
        if (pass && d[k] < nv){ nv = d[k]; nn2 = n; } } \
      gv[(J)] = nv; gn[(J)] = nn2; }
    RECOMP(0) RECOMP(1) RECOMP(2) RECOMP(3)
    RECOMP(4) RECOMP(5) RECOMP(6) RECOMP(7)
    #undef RECOMP
  }
  __syncthreads();

  const float* pb = points + b * DD * NN;
  float fm = -GINF, xm = -GINF, ym = -GINF, zm = -GINF;
  #pragma unroll 8
  for (int j = 0; j < KK; ++j){
    int nj = nbr[wslot][j];
    fm = fmaxf(fm, pb[lane * NN + nj]);
    xm = fmaxf(xm, xb[nj]);
    ym = fmaxf(ym, xb[NN + nj]);
    zm = fmaxf(zm, xb[2 * NN + nj]);
  }
  float* out1 = out + BB * 3 * SS;
  float* o1b  = out1 + b * 67 * SS;
  o1b[(3 + lane) * SS + cs] = fm;
  if (lane == 0){
    o1b[cs] = xm; o1b[SS + cs] = ym; o1b[2 * SS + cs] = zm;
    float* o0b = out + b * 3 * SS;
    o0b[cs] = cx; o0b[SS + cs] = cy; o0b[2 * SS + cs] = cz;
  }
}

extern "C" void kernel_launch(void* const* d_in, const int* in_sizes, int n_in,
                              void* d_out, int out_size, void* d_ws, size_t ws_size,
                              hipStream_t stream){
  const float* xyz    = (const float*)d_in[0];
  const float* points = (const float*)d_in[1];
  const int*   finit  = (const int*)d_in[2];
  float* out = (float*)d_out;
  int*   fps_idx = (int*)d_ws;                               // 8*1024 ints
  float* sqx     = (float*)((char*)d_ws + BB * SS * sizeof(int)); // 8*4096 floats

  hipLaunchKernelGGL(sqx_kernel, dim3(BB * NN / 256), dim3(256), 0, stream, xyz, sqx);
  hipLaunchKernelGGL(fps_kernel, dim3(BB / 2), dim3(256), 0, stream, xyz, finit, fps_idx);
  hipLaunchKernelGGL(knn_kernel, dim3(BB * SS / 4), dim3(256), 0, stream,
                     xyz, points, sqx, fps_idx, out);
}